// Round 11
// baseline (165.526 us; speedup 1.0000x reference)
//
#include <hip/hip_runtime.h>

// Decimate-by-4, 129-tap windowed-sinc. ABLATION ROUND:
//   V0 (real, -> d_out): r10 pipeline + sched_barrier(0) pinning stage issue.
//   V1 (diag): stage-only timeline (4 tiles, barriers, no compute).
//   V2 (diag): compute-only timeline (stage once, 4x compute, no stores).
// Headline dur = sum of all three (diagnostic round); per-dispatch rocprof
// rows give the marginal costs.

#define T_LEN 1048576
#define OUT_PER_ROW (T_LEN / 4)                       // 262144
#define C 8
#define BLOCK 256
#define OUT_PER_TILE (BLOCK * C)                      // 2048
#define TILES_PER_ROW (OUT_PER_ROW / OUT_PER_TILE)    // 128
#define NCHUNK (OUT_PER_TILE + 32)                    // 2080 float4 chunks
#define BUF_BYTES (NCHUNK * 16)                       // 33280
#define TPB 4

__device__ __forceinline__ unsigned swz(unsigned q) {
  return q ^ ((q >> 3) & 0x70u);                      // involution, 16B-aligned safe
}

__device__ __forceinline__ void gload_lds16(const void* g, void* l) {
  __builtin_amdgcn_global_load_lds(
      (const __attribute__((address_space(1))) void*)g,
      (__attribute__((address_space(3))) void*)l, 16, 0, 0);
}

__device__ __forceinline__ void stage_tile(const float* __restrict__ x,
                                           int gt, char* s_buf, int tid) {
  const int row = gt >> 7;
  const int blk = gt & (TILES_PER_ROW - 1);
  const float* xr = x + (size_t)row * T_LEN;
  const int win0 = 4 * blk * OUT_PER_TILE - 64;

  if (blk != 0 && blk != TILES_PER_ROW - 1) {
    const char* gb = (const char*)(xr + win0);
    #pragma unroll
    for (int g = 0; g < 8; ++g) {
      unsigned lq = (unsigned)(g * BLOCK + tid) * 16u;
      gload_lds16(gb + swz(lq), s_buf + lq);
    }
    if (tid < NCHUNK - 8 * BLOCK) {
      unsigned lq = (unsigned)(8 * BLOCK + tid) * 16u;
      gload_lds16(gb + swz(lq), s_buf + lq);
    }
  } else {
    for (int i = tid; i < NCHUNK; i += BLOCK) {
      unsigned lq = (unsigned)i * 16u;
      float v[4];
      #pragma unroll
      for (int p = 0; p < 4; ++p) {
        int g = win0 + 4 * i + p;
        float t = 0.0f;
        if (g < 0) t = xr[-g];
        else if (g < T_LEN) t = xr[g];
        v[p] = t;
      }
      *(float4*)(s_buf + swz(lq)) = make_float4(v[0], v[1], v[2], v[3]);
    }
  }
}

__device__ __forceinline__ void compute_acc(const float* __restrict__ kk,
                                            const char* s_buf, int tid,
                                            float acc[C]) {
  #pragma unroll
  for (int i = 0; i < C; ++i) acc[i] = 0.0f;
  const unsigned qb = (unsigned)(tid * C) * 16u;
  #pragma unroll
  for (int n = 0; n < 40; ++n) {
    unsigned q = qb + (unsigned)n * 16u;
    const float4 w = *(const float4*)(s_buf + swz(q));
    #pragma unroll
    for (int c = 0; c < C; ++c) {
      const int e = n - c;
      if (e < 0 || e > 32) continue;
      if (e == 32) {
        acc[c] = fmaf(kk[128], w.x, acc[c]);
      } else {
        acc[c] = fmaf(kk[4 * e + 0], w.x, acc[c]);
        acc[c] = fmaf(kk[4 * e + 1], w.y, acc[c]);
        acc[c] = fmaf(kk[4 * e + 2], w.z, acc[c]);
        acc[c] = fmaf(kk[4 * e + 3], w.w, acc[c]);
      }
    }
  }
}

// ---------- V0: real kernel (pipeline + pinned stage issue) ----------
__global__ __launch_bounds__(BLOCK, 2) void decim_v0(
    const float* __restrict__ x, const float* __restrict__ kk,
    float* __restrict__ out) {
  __shared__ __align__(128) char s_mem[2 * BUF_BYTES];
  const int tid = threadIdx.x;
  const int t0 = blockIdx.x * TPB;

  stage_tile(x, t0, s_mem, tid);
  __builtin_amdgcn_sched_barrier(0);                  // pin prologue issue
  __syncthreads();

  int cur = 0;
  #pragma unroll 1
  for (int t = 0; t < TPB; ++t) {
    if (t + 1 < TPB) {
      stage_tile(x, t0 + t + 1, s_mem + (cur ^ 1) * BUF_BYTES, tid);
      __builtin_amdgcn_sched_barrier(0);              // forbid sinking the loads
    }
    float acc[C];
    compute_acc(kk, s_mem + cur * BUF_BYTES, tid, acc);
    const int gt = t0 + t;
    float* op = out + (size_t)(gt >> 7) * OUT_PER_ROW +
                (gt & (TILES_PER_ROW - 1)) * OUT_PER_TILE + tid * C;
    *(float4*)(op)     = make_float4(acc[0], acc[1], acc[2], acc[3]);
    *(float4*)(op + 4) = make_float4(acc[4], acc[5], acc[6], acc[7]);
    __syncthreads();
    cur ^= 1;
  }
}

// ---------- V1: stage-only (staging timeline, no compute) ----------
__global__ __launch_bounds__(BLOCK, 2) void stage_v1(
    const float* __restrict__ x) {
  __shared__ __align__(128) char s_mem[2 * BUF_BYTES];
  const int tid = threadIdx.x;
  const int t0 = blockIdx.x * TPB;
  #pragma unroll 1
  for (int t = 0; t < TPB; ++t) {
    stage_tile(x, t0 + t, s_mem + (t & 1) * BUF_BYTES, tid);
    __syncthreads();
  }
}

// ---------- V2: compute-only (stage once, 4x compute, no stores) ----------
__global__ __launch_bounds__(BLOCK, 2) void comp_v2(
    const float* __restrict__ x, const float* __restrict__ kk) {
  __shared__ __align__(128) char s_mem[2 * BUF_BYTES];
  const int tid = threadIdx.x;
  const int t0 = blockIdx.x * TPB;

  stage_tile(x, t0, s_mem, tid);
  __syncthreads();

  #pragma unroll 1
  for (int t = 0; t < TPB; ++t) {
    float acc[C];
    compute_acc(kk, s_mem, tid, acc);
    #pragma unroll
    for (int i = 0; i < C; ++i)
      asm volatile("" : : "v"(acc[i]));               // keep live (rule #17)
    __syncthreads();
  }
}

extern "C" void kernel_launch(void* const* d_in, const int* in_sizes, int n_in,
                              void* d_out, int out_size, void* d_ws, size_t ws_size,
                              hipStream_t stream) {
  const float* x = (const float*)d_in[0];
  const float* k = (const float*)d_in[1];
  float* out = (float*)d_out;
  const int rows = in_sizes[0] / T_LEN;               // 16
  dim3 grid(rows * TILES_PER_ROW / TPB);              // 512 blocks each

  decim_v0<<<grid, BLOCK, 0, stream>>>(x, k, out);    // real result
  stage_v1<<<grid, BLOCK, 0, stream>>>(x);            // diag: staging cost
  comp_v2<<<grid, BLOCK, 0, stream>>>(x, k);          // diag: compute cost
}